// Round 5
// baseline (348.277 us; speedup 1.0000x reference)
//
#include <hip/hip_runtime.h>
#include <hip/hip_bf16.h>

// ---------------------------------------------------------------------------
// MultiheadAttention (B=4, S=8192, E=1024, H=16, D=64) — bf16 MFMA,
// BARRIER-FREE design: all MFMA kernels read fragments directly from global
// (operands are small & L2-resident); no __syncthreads in any GEMM K-loop,
// so no vmcnt(0) barrier drains — latency is hidden by per-wave MLP.
//
//   qkv = x @ [Wq*0.125 | Wk | Wv]^T + [bq*0.125 | bk | bv]   (bf16, 32768x192)
//   Qh[b,h,i,d] = qkv[b*8192 + i*16 + h][d]      (S' = 512)
//   Kc[bh][key][d], Vt[bh][d][key]  (compact per-head copies, one pass)
//   fused: ctx[b*512+i][h*64+d] = softmax(Qh Kh^T) @ Vh   (no score buffer)
//   out = ctx @ Wo^T + bo (fp32)
//
// MFMA 16x16x32 bf16 layouts (m89/m91-verified):
//   A frag: lane q*16+r holds A[m=r][k=q*8+j]
//   B frag: lane q*16+r holds B[n=r][k=q*8+j]   (B n-major)
//   C/D   : lane q*16+r holds D[row=q*4+e][col=r]
// All direct frag loads are 16B/lane with q (lanes 0-3 within each 16-lane
// group) covering 64B consecutive -> full-line utilization.
// ---------------------------------------------------------------------------

typedef unsigned short u16;
typedef __attribute__((ext_vector_type(8))) short short8;
typedef __attribute__((ext_vector_type(4))) float f32x4;

__device__ inline u16 f2bf(float f) {
    union { float f; unsigned u; } v; v.f = f;
    unsigned u = v.u;
    return (u16)((u + 0x7fffu + ((u >> 16) & 1u)) >> 16);  // RNE
}
__device__ inline unsigned pack_bf2(float a, float b) {
    union { __hip_bfloat162 h; unsigned u; } v;
    v.h = __float22bfloat162_rn(float2{a, b});
    return v.u;
}

// ---------------------------------------------------------------------------
// Weight/bias conversion.
// ---------------------------------------------------------------------------
__global__ __launch_bounds__(256) void convw(
    const float* __restrict__ Wq, const float* __restrict__ bq,
    const float* __restrict__ Wk, const float* __restrict__ bk,
    const float* __restrict__ Wv, const float* __restrict__ bv,
    const float* __restrict__ Wo,
    u16* __restrict__ Wqkv, float* __restrict__ qkvb, u16* __restrict__ Wob)
{
    const int idx = blockIdx.x * 256 + threadIdx.x;   // 0 .. 1048575
    Wob[idx] = f2bf(Wo[idx]);
    if (idx < 196608) {
        const int row = idx >> 10, k = idx & 1023;
        float v = (row < 64)  ? Wq[row * 1024 + k] * 0.125f
                : (row < 128) ? Wk[(row - 64) * 1024 + k]
                              : Wv[(row - 128) * 1024 + k];
        Wqkv[idx] = f2bf(v);
    }
    if (idx < 192) {
        qkvb[idx] = (idx < 64) ? bq[idx] * 0.125f
                  : (idx < 128) ? bk[idx - 64] : bv[idx - 128];
    }
}

// ---------------------------------------------------------------------------
// Fused QKV projection, barrier-free: qkv[32768][192] = bf16(X) @ Wqkv^T + b.
// 512 blocks x 4 waves; wave owns 16 rows x all 192 cols (12 n-tiles).
// A frags: direct fp32 global loads + in-reg pack (each lane's 32B IS its
// fragment). B frags: direct bf16 global loads (W = 384 KB, L2-hot).
// No LDS, no __syncthreads.
// ---------------------------------------------------------------------------
__global__ __launch_bounds__(256, 2) void qkv_gemm(
    const float* __restrict__ X, const u16* __restrict__ W,
    const float* __restrict__ bias, u16* __restrict__ Out)
{
    const int tid = threadIdx.x;
    const int lane = tid & 63, wid = tid >> 6;
    const int q = lane >> 4, r = lane & 15;
    const long m0 = (long)blockIdx.x * 64;

    const float* px = X + (m0 + wid * 16 + r) * 1024 + q * 8;
    const u16*   pb = W + (long)r * 1024 + q * 8;   // + nt*16*1024 + k0

    f32x4 acc[12] = {};

    #pragma unroll 2
    for (int k0 = 0; k0 < 1024; k0 += 32) {
        float4 a0 = *(const float4*)(px + k0);
        float4 a1 = *(const float4*)(px + k0 + 4);
        union { short8 s; unsigned u[4]; } af;
        af.u[0] = pack_bf2(a0.x, a0.y);
        af.u[1] = pack_bf2(a0.z, a0.w);
        af.u[2] = pack_bf2(a1.x, a1.y);
        af.u[3] = pack_bf2(a1.z, a1.w);
        #pragma unroll
        for (int nt = 0; nt < 12; ++nt) {
            short8 bf = *(const short8*)(pb + nt * 16384 + k0);
            acc[nt] = __builtin_amdgcn_mfma_f32_16x16x32_bf16(
                af.s, bf, acc[nt], 0, 0, 0);
        }
    }

    #pragma unroll
    for (int nt = 0; nt < 12; ++nt) {
        const int col = nt * 16 + r;
        const float badd = bias[col];
        #pragma unroll
        for (int e = 0; e < 4; ++e) {
            const long row = m0 + wid * 16 + q * 4 + e;
            Out[row * 192 + col] = f2bf(acc[nt][e] + badd);
        }
    }
}

// ---------------------------------------------------------------------------
// K compact + V transpose, one pass over the K/V thirds of qkv:
//   Kc[bh*512 + i][d]  <- qkv[b*8192 + i*16 + h][64  + d]   (copy, coalesced)
//   Vt[bh*64  + d][i]  <- qkv[b*8192 + i*16 + h][128 + d]   (LDS transpose)
// ---------------------------------------------------------------------------
__global__ __launch_bounds__(256) void kvtrans(
    const u16* __restrict__ qkv, u16* __restrict__ Kc, u16* __restrict__ Vt)
{
    __shared__ u16 T[64][68];
    const int bh = blockIdx.x, b = bh >> 4, h = bh & 15;
    const int i0 = blockIdx.y * 64;
    const int tid = threadIdx.x;

    #pragma unroll
    for (int it = 0; it < 2; ++it) {
        const int c = tid + 256 * it;                 // 0..511
        const int il = c >> 3, d8 = (c & 7) * 8;
        const u16* src = qkv + ((long)b * 8192 + (long)(i0 + il) * 16 + h) * 192;
        // K compact copy
        short8 kv = *(const short8*)(src + 64 + d8);
        *(short8*)(Kc + ((long)bh * 512 + i0 + il) * 64 + d8) = kv;
        // V into LDS tile
        short8 vv = *(const short8*)(src + 128 + d8);
        #pragma unroll
        for (int j = 0; j < 8; ++j) T[d8 + j][il] = (u16)vv[j];
    }
    __syncthreads();
    #pragma unroll
    for (int it = 0; it < 2; ++it) {
        const int c = tid + 256 * it;
        const int dl = c >> 3, i8 = (c & 7) * 8;
        short8 o;
        #pragma unroll
        for (int j = 0; j < 8; ++j) o[j] = (short)T[dl][i8 + j];
        *(short8*)(Vt + ((long)bh * 64 + dl) * 512 + i0 + i8) = o;
    }
}

// ---------------------------------------------------------------------------
// Fused flash attention, barrier-free: block = (q-tile of 64, bh); 4 waves,
// 16 Q-rows each. K frags from Kc, V frags from Vt — direct global loads
// (L2-hot: 128 KB/head working set, reused by 8 q-tile blocks). Online
// softmax in registers; P C-layout -> A-frag via wave-private LDS (stride 72,
// no barrier needed).
// ---------------------------------------------------------------------------
__global__ __launch_bounds__(256, 2) void attn_flash(
    const u16* __restrict__ qkv, const u16* __restrict__ Kc,
    const u16* __restrict__ Vt, u16* __restrict__ ctx)
{
    __shared__ u16 Plds[4][16 * 72];   // wave-private P transform

    const int tid = threadIdx.x, lane = tid & 63, wid = tid >> 6;
    const int q = lane >> 4, r = lane & 15;
    const int qt = blockIdx.x;         // 0..7
    const int bh = blockIdx.y;         // 0..63
    const int b = bh >> 4, h = bh & 15;
    const long qrowbase = (long)b * 8192 + h;

    // Q A-fragments (d = 0..63 -> 2 frags), direct from qkv
    short8 Qf0, Qf1;
    {
        const int i = qt * 64 + wid * 16 + r;
        const u16* p = qkv + (qrowbase + (long)i * 16) * 192 + q * 8;
        Qf0 = *(const short8*)(p);
        Qf1 = *(const short8*)(p + 32);
    }

    const u16* kb = Kc + ((long)bh * 512 + r) * 64 + q * 8;   // + key*64 + f*32
    const u16* vb = Vt + ((long)bh * 64 + r) * 512 + q * 8;   // + nt*16*512 + j0 + f*32

    f32x4 O[4] = {};
    float mrun[4] = {-1e30f, -1e30f, -1e30f, -1e30f};
    float lrun[4] = {};
    u16* Pw = &Plds[wid][0];

    for (int j0 = 0; j0 < 512; j0 += 64) {
        // ---- scores chunk S[16 rows][64 keys] ----
        f32x4 S[4];
        #pragma unroll
        for (int ct = 0; ct < 4; ++ct) {
            const u16* p = kb + (long)(j0 + ct * 16) * 64;
            short8 k0 = *(const short8*)(p);
            short8 k1 = *(const short8*)(p + 32);
            f32x4 s = {};
            s = __builtin_amdgcn_mfma_f32_16x16x32_bf16(Qf0, k0, s, 0, 0, 0);
            s = __builtin_amdgcn_mfma_f32_16x16x32_bf16(Qf1, k1, s, 0, 0, 0);
            S[ct] = s;
        }
        // ---- online softmax update (row = (q,e); reduce over r, ct) ----
        #pragma unroll
        for (int e = 0; e < 4; ++e) {
            float mc = fmaxf(fmaxf(S[0][e], S[1][e]), fmaxf(S[2][e], S[3][e]));
            #pragma unroll
            for (int off = 1; off < 16; off <<= 1)
                mc = fmaxf(mc, __shfl_xor(mc, off, 64));
            const float mnew = fmaxf(mrun[e], mc);
            const float alpha = __expf(mrun[e] - mnew);
            mrun[e] = mnew;
            float se = 0.f;
            #pragma unroll
            for (int ct = 0; ct < 4; ++ct) {
                const float pv = __expf(S[ct][e] - mnew);
                S[ct][e] = pv; se += pv;
            }
            #pragma unroll
            for (int off = 1; off < 16; off <<= 1)
                se += __shfl_xor(se, off, 64);
            lrun[e] = lrun[e] * alpha + se;
            #pragma unroll
            for (int nt = 0; nt < 4; ++nt) O[nt][e] *= alpha;
        }
        // ---- P: C-layout -> LDS [m][k] (stride 72) -> A-frags ----
        #pragma unroll
        for (int e = 0; e < 4; ++e)
            #pragma unroll
            for (int ct = 0; ct < 4; ++ct)
                Pw[(q * 4 + e) * 72 + ct * 16 + r] = f2bf(S[ct][e]);
        short8 Pf0 = *(const short8*)(Pw + r * 72 + q * 8);
        short8 Pf1 = *(const short8*)(Pw + r * 72 + 32 + q * 8);
        // ---- O += P @ V ----
        #pragma unroll
        for (int nt = 0; nt < 4; ++nt) {
            const u16* p = vb + (long)nt * 16 * 512 + j0;
            short8 v0 = *(const short8*)(p);
            short8 v1 = *(const short8*)(p + 32);
            O[nt] = __builtin_amdgcn_mfma_f32_16x16x32_bf16(Pf0, v0, O[nt], 0, 0, 0);
            O[nt] = __builtin_amdgcn_mfma_f32_16x16x32_bf16(Pf1, v1, O[nt], 0, 0, 0);
        }
    }

    // ---- epilogue: normalize, write ctx[b*512+i][h*64+d] ----
    #pragma unroll
    for (int e = 0; e < 4; ++e) {
        const float inv = 1.0f / lrun[e];
        const long i = qt * 64 + wid * 16 + q * 4 + e;
        u16* po = ctx + ((long)b * 512 + i) * 1024 + h * 64 + r;
        #pragma unroll
        for (int nt = 0; nt < 4; ++nt)
            po[nt * 16] = f2bf(O[nt][e] * inv);
    }
}

// ---------------------------------------------------------------------------
// Output projection, barrier-free: out[2048][1024] fp32 = ctx @ Wob^T + bo.
// 512 blocks x 4 waves (2x2); wave = 32m x 32n, frags direct from global
// (ctx 4 MB + Wob 2 MB, L2-resident). No LDS, no __syncthreads.
// ---------------------------------------------------------------------------
__global__ __launch_bounds__(256, 2) void gemm_o(
    const u16* __restrict__ A, const u16* __restrict__ B,
    const float* __restrict__ bias, float* __restrict__ C)
{
    const int tid = threadIdx.x;
    const int lane = tid & 63, wid = tid >> 6;
    const int q = lane >> 4, r = lane & 15;
    const long m0 = (long)blockIdx.x * 64, n0 = (long)blockIdx.y * 64;
    const int wm = wid >> 1, wn = wid & 1;

    const u16* pa0 = A + (m0 + (wm * 2 + 0) * 16 + r) * 1024 + q * 8;
    const u16* pa1 = A + (m0 + (wm * 2 + 1) * 16 + r) * 1024 + q * 8;
    const u16* pb0 = B + (n0 + (wn * 2 + 0) * 16 + r) * 1024 + q * 8;
    const u16* pb1 = B + (n0 + (wn * 2 + 1) * 16 + r) * 1024 + q * 8;

    f32x4 acc[2][2] = {};

    #pragma unroll 2
    for (int k0 = 0; k0 < 1024; k0 += 32) {
        short8 af0 = *(const short8*)(pa0 + k0);
        short8 af1 = *(const short8*)(pa1 + k0);
        short8 bf0 = *(const short8*)(pb0 + k0);
        short8 bf1 = *(const short8*)(pb1 + k0);
        acc[0][0] = __builtin_amdgcn_mfma_f32_16x16x32_bf16(af0, bf0, acc[0][0], 0, 0, 0);
        acc[0][1] = __builtin_amdgcn_mfma_f32_16x16x32_bf16(af0, bf1, acc[0][1], 0, 0, 0);
        acc[1][0] = __builtin_amdgcn_mfma_f32_16x16x32_bf16(af1, bf0, acc[1][0], 0, 0, 0);
        acc[1][1] = __builtin_amdgcn_mfma_f32_16x16x32_bf16(af1, bf1, acc[1][1], 0, 0, 0);
    }

    #pragma unroll
    for (int i = 0; i < 2; ++i)
        #pragma unroll
        for (int j = 0; j < 2; ++j) {
            const long col = n0 + (wn * 2 + j) * 16 + r;
            const float badd = bias[col];
            #pragma unroll
            for (int e = 0; e < 4; ++e) {
                const long row = m0 + (wm * 2 + i) * 16 + q * 4 + e;
                C[row * 1024 + col] = acc[i][j][e] + badd;
            }
        }
}

// ---------------------------------------------------------------------------
extern "C" void kernel_launch(void* const* d_in, const int* in_sizes, int n_in,
                              void* d_out, int out_size, void* d_ws, size_t ws_size,
                              hipStream_t stream)
{
    const float* x  = (const float*)d_in[0];
    const float* Wq = (const float*)d_in[1];
    const float* bq = (const float*)d_in[2];
    const float* Wk = (const float*)d_in[3];
    const float* bk = (const float*)d_in[4];
    const float* Wv = (const float*)d_in[5];
    const float* bv = (const float*)d_in[6];
    const float* Wo = (const float*)d_in[7];
    const float* bo = (const float*)d_in[8];
    float* out = (float*)d_out;
    char* ws = (char*)d_ws;

    u16*   qkv  = (u16*)(ws);                   // 32768*192*2   = 12,582,912
    u16*   Vt   = (u16*)(ws + 12582912);        // 64*64*512*2   =  4,194,304
    u16*   Kc   = (u16*)(ws + 16777216);        // 64*512*64*2   =  4,194,304
    u16*   Wqkv = (u16*)(ws + 20971520);        // 192*1024*2    =    393,216
    u16*   Wob  = (u16*)(ws + 21364736);        // 1024*1024*2   =  2,097,152
    float* qkvb = (float*)(ws + 23461888);      // 192*4
    u16*   ctx  = (u16*)(ws + 23462656);        // 2048*1024*2   =  4,194,304

    convw<<<4096, 256, 0, stream>>>(Wq, bq, Wk, bk, Wv, bv, Wo, Wqkv, qkvb, Wob);
    qkv_gemm<<<512, 256, 0, stream>>>(x, Wqkv, qkvb, qkv);
    kvtrans<<<dim3(64, 8), 256, 0, stream>>>(qkv, Kc, Vt);
    attn_flash<<<dim3(8, 64), 256, 0, stream>>>(qkv, Kc, Vt, ctx);
    gemm_o<<<dim3(32, 16), 256, 0, stream>>>(ctx, Wob, bo, out);
}

// Round 6
// 263.825 us; speedup vs baseline: 1.3201x; 1.3201x over previous
//
#include <hip/hip_runtime.h>
#include <hip/hip_bf16.h>

// ---------------------------------------------------------------------------
// MultiheadAttention (B=4, S=8192, E=1024, H=16, D=64) — bf16 MFMA.
// R6: async global_load_lds staging everywhere (R5 showed direct-global frag
// loads are latency-death: MfmaUtil 3.8%); qkv BK=64 dbuf; attention computes
// S^T (K as A-operand) so softmax reduces with 2 shuffles and P/ctx writes
// are packed.
//
//   qkv = x @ [Wq*0.125 | Wk | Wv]^T + [bq*0.125 | bk | bv]   (bf16, 32768x192)
//   Qh[b,h,i,d] = qkv[b*8192 + i*16 + h][d]      (S' = 512)
//   fused: ctx[b*512+i][h*64+d] = softmax(Qh Kh^T) @ Vh   (no score buffer)
//   out = ctx @ Wo^T + bo (fp32)
//
// MFMA 16x16x32 bf16 layouts (m89/m91-verified):
//   A frag: lane q*16+r holds A[m=r][k=q*8+j]
//   B frag: lane q*16+r holds B[n=r][k=q*8+j]
//   C/D   : lane q*16+r holds D[row=q*4+e][col=r]
// ---------------------------------------------------------------------------

typedef unsigned short u16;
typedef __attribute__((ext_vector_type(8))) short short8;
typedef __attribute__((ext_vector_type(4))) float f32x4;

__device__ inline u16 f2bf(float f) {
    union { float f; unsigned u; } v; v.f = f;
    unsigned u = v.u;
    return (u16)((u + 0x7fffu + ((u >> 16) & 1u)) >> 16);  // RNE
}
__device__ inline unsigned pack_bf2(float a, float b) {
    union { __hip_bfloat162 h; unsigned u; } v;
    v.h = __float22bfloat162_rn(float2{a, b});
    return v.u;
}
// Async global->LDS, 16 B per lane. LDS dest = wave-uniform base + lane*16.
__device__ __forceinline__ void gld16(void* lds, const void* gptr) {
    __builtin_amdgcn_global_load_lds(
        (const __attribute__((address_space(1))) unsigned int*)gptr,
        (__attribute__((address_space(3))) unsigned int*)lds,
        16, 0, 0);
}

// ---------------------------------------------------------------------------
// Weight/bias conversion.
// ---------------------------------------------------------------------------
__global__ __launch_bounds__(256) void convw(
    const float* __restrict__ Wq, const float* __restrict__ bq,
    const float* __restrict__ Wk, const float* __restrict__ bk,
    const float* __restrict__ Wv, const float* __restrict__ bv,
    const float* __restrict__ Wo,
    u16* __restrict__ Wqkv, float* __restrict__ qkvb, u16* __restrict__ Wob)
{
    const int idx = blockIdx.x * 256 + threadIdx.x;   // 0 .. 1048575
    Wob[idx] = f2bf(Wo[idx]);
    if (idx < 196608) {
        const int row = idx >> 10, k = idx & 1023;
        float v = (row < 64)  ? Wq[row * 1024 + k] * 0.125f
                : (row < 128) ? Wk[(row - 64) * 1024 + k]
                              : Wv[(row - 128) * 1024 + k];
        Wqkv[idx] = f2bf(v);
    }
    if (idx < 192) {
        qkvb[idx] = (idx < 64) ? bq[idx] * 0.125f
                  : (idx < 128) ? bk[idx - 64] : bv[idx - 128];
    }
}

// ---------------------------------------------------------------------------
// Fused QKV projection: qkv[32768][192] = bf16(X fp32) @ Wqkv^T + b.
// 512 blocks x 4 waves; wave w owns m-tile w (16 rows) x 192 cols.
// BK=64: B staged via global_load_lds (24 sections of 64 slots; 6 per wave),
// double-buffered, ONE barrier per step (16 total). A frags are per-wave
// private: direct fp32 loads + in-reg pack, register-prefetched.
// ---------------------------------------------------------------------------
__global__ __launch_bounds__(256) void qkv_gemm(
    const float* __restrict__ X, const u16* __restrict__ W,
    const float* __restrict__ bias, u16* __restrict__ Out)
{
    __shared__ short8 Bs[2][1536];   // [p*64 + lane], p = kk2*12 + nt

    const int tid = threadIdx.x;
    const int lane = tid & 63, wid = tid >> 6;
    const int q = lane >> 4, r = lane & 15;
    const long m0 = (long)blockIdx.x * 64;

    // B staging pointers: this wave covers p = wid*6 .. wid*6+5
    const u16* wp[6];
    #pragma unroll
    for (int i = 0; i < 6; ++i) {
        const int p = wid * 6 + i, kk2 = p / 12, nt = p % 12;
        wp[i] = W + (long)(nt * 16 + r) * 1024 + kk2 * 32 + q * 8;
    }

    const float* px = X + (m0 + wid * 16 + r) * 1024 + q * 8;

    f32x4 acc[12] = {};

    // prologue: stage step 0 into buf 0; load step-0 A regs
    #pragma unroll
    for (int i = 0; i < 6; ++i)
        gld16(&Bs[0][(wid * 6 + i) * 64], wp[i]);
    float4 a[4];
    a[0] = *(const float4*)(px);
    a[1] = *(const float4*)(px + 4);
    a[2] = *(const float4*)(px + 32);
    a[3] = *(const float4*)(px + 36);
    __syncthreads();

    for (int k0 = 0; k0 < 1024; k0 += 64) {
        const int buf = (k0 >> 6) & 1;
        float4 an[4] = {};
        if (k0 + 64 < 1024) {
            #pragma unroll
            for (int i = 0; i < 6; ++i)
                gld16(&Bs[buf ^ 1][(wid * 6 + i) * 64], wp[i] + k0 + 64);
            an[0] = *(const float4*)(px + k0 + 64);
            an[1] = *(const float4*)(px + k0 + 68);
            an[2] = *(const float4*)(px + k0 + 96);
            an[3] = *(const float4*)(px + k0 + 100);
        }
        #pragma unroll
        for (int kk2 = 0; kk2 < 2; ++kk2) {
            union { short8 s; unsigned u[4]; } af;
            af.u[0] = pack_bf2(a[kk2 * 2].x, a[kk2 * 2].y);
            af.u[1] = pack_bf2(a[kk2 * 2].z, a[kk2 * 2].w);
            af.u[2] = pack_bf2(a[kk2 * 2 + 1].x, a[kk2 * 2 + 1].y);
            af.u[3] = pack_bf2(a[kk2 * 2 + 1].z, a[kk2 * 2 + 1].w);
            #pragma unroll
            for (int nt = 0; nt < 12; ++nt)
                acc[nt] = __builtin_amdgcn_mfma_f32_16x16x32_bf16(
                    af.s, Bs[buf][(kk2 * 12 + nt) * 64 + lane], acc[nt], 0, 0, 0);
        }
        __syncthreads();
        #pragma unroll
        for (int i = 0; i < 4; ++i) a[i] = an[i];
    }

    #pragma unroll
    for (int nt = 0; nt < 12; ++nt) {
        const int col = nt * 16 + r;
        const float badd = bias[col];
        #pragma unroll
        for (int e = 0; e < 4; ++e) {
            const long row = m0 + wid * 16 + q * 4 + e;
            Out[row * 192 + col] = f2bf(acc[nt][e] + badd);
        }
    }
}

// ---------------------------------------------------------------------------
// V transpose: Vt[bh*64 + d][i] <- qkv[b*8192 + i*16 + h][128 + d]
// ---------------------------------------------------------------------------
__global__ __launch_bounds__(256) void vtrans(
    const u16* __restrict__ qkv, u16* __restrict__ Vt)
{
    __shared__ u16 T[64][68];
    const int bh = blockIdx.x, b = bh >> 4, h = bh & 15;
    const int i0 = blockIdx.y * 64;
    const int tid = threadIdx.x;

    #pragma unroll
    for (int it = 0; it < 2; ++it) {
        const int c = tid + 256 * it;
        const int il = c >> 3, d8 = (c & 7) * 8;
        short8 v = *(const short8*)(qkv +
            ((long)b * 8192 + (long)(i0 + il) * 16 + h) * 192 + 128 + d8);
        #pragma unroll
        for (int j = 0; j < 8; ++j) T[d8 + j][il] = (u16)v[j];
    }
    __syncthreads();
    #pragma unroll
    for (int it = 0; it < 2; ++it) {
        const int c = tid + 256 * it;
        const int dl = c >> 3, i8 = (c & 7) * 8;
        short8 o;
        #pragma unroll
        for (int j = 0; j < 8; ++j) o[j] = (short)T[dl][i8 + j];
        *(short8*)(Vt + ((long)bh * 64 + dl) * 512 + i0 + i8) = o;
    }
}

// ---------------------------------------------------------------------------
// Fused flash attention, S^T formulation. Block = (q-tile of 64, bh); 4
// waves, 16 queries each. K/V chunks (64 keys) in double-buffered LDS via
// global_load_lds, prefetched one chunk ahead, one barrier per chunk.
//   S^T = MFMA(A=K, B=Q): lane(q,r) holds S^T[key=ct*16+q*4+e][query=r]
//   -> softmax over keys = 15 in-lane ops + 2 shuffles (XOR 16,32)
//   -> m/l/alpha are per-lane scalars (query = r)
//   P^T packed to LDS as P[query][key] (stride 72) with b64 writes;
//   O^T = MFMA(A=V^T, B=P): lane holds O^T[d=nt*16+q*4+e][query=r].
// ---------------------------------------------------------------------------
__global__ __launch_bounds__(256) void attn_flash(
    const u16* __restrict__ qkv, const u16* __restrict__ Vt,
    u16* __restrict__ ctx)
{
    __shared__ short8 Ks[2][512];      // [f*256 + ct*64 + q*16 + r]
    __shared__ short8 Vs[2][512];      // [f*256 + nt*64 + q*16 + r]
    __shared__ u16 Plds[4][16 * 72];   // wave-private P[query][key]

    const int tid = threadIdx.x, lane = tid & 63, wid = tid >> 6;
    const int q = lane >> 4, r = lane & 15;
    const int qt = blockIdx.x;         // 0..7
    const int bh = blockIdx.y;         // 0..63
    const int b = bh >> 4, h = bh & 15;
    const long qrowbase = (long)b * 8192 + h;

    // Q B-fragments: lane(q,r) needs Q[query=r][d=q*8+j] (2 d-halves)
    short8 Qf0, Qf1;
    {
        const int i = qt * 64 + wid * 16 + r;
        const u16* p = qkv + (qrowbase + (long)i * 16) * 192 + q * 8;
        Qf0 = *(const short8*)(p);
        Qf1 = *(const short8*)(p + 32);
    }

    // staging pointers (this thread: key/row = wid*16 + r, d-octet q)
    const u16* kbase = qkv + (qrowbase + (long)(wid * 16 + r) * 16) * 192
                           + 64 + q * 8;                 // + key*3072 + f*32
    const u16* vbase = Vt + ((long)bh * 64 + wid * 16 + r) * 512 + q * 8;

    gld16(&Ks[0][wid * 64],       kbase);
    gld16(&Ks[0][256 + wid * 64], kbase + 32);
    gld16(&Vs[0][wid * 64],       vbase);
    gld16(&Vs[0][256 + wid * 64], vbase + 32);
    __syncthreads();

    f32x4 O[4] = {};
    float mrun = -1e30f, lrun = 0.f;   // per-lane scalars (query = r)
    u16* Pw = &Plds[wid][0];

    for (int c = 0; c < 8; ++c) {
        const int j0 = c * 64, buf = c & 1;
        if (c < 7) {
            const u16* kp = kbase + (long)(j0 + 64) * 3072;
            const u16* vp = vbase + j0 + 64;
            gld16(&Ks[buf ^ 1][wid * 64],       kp);
            gld16(&Ks[buf ^ 1][256 + wid * 64], kp + 32);
            gld16(&Vs[buf ^ 1][wid * 64],       vp);
            gld16(&Vs[buf ^ 1][256 + wid * 64], vp + 32);
        }
        // ---- S^T chunk: lane holds S^T[key=ct*16+q*4+e][query r] ----
        f32x4 S[4];
        #pragma unroll
        for (int ct = 0; ct < 4; ++ct) {
            f32x4 s = {};
            s = __builtin_amdgcn_mfma_f32_16x16x32_bf16(
                Ks[buf][ct * 64 + lane], Qf0, s, 0, 0, 0);
            s = __builtin_amdgcn_mfma_f32_16x16x32_bf16(
                Ks[buf][256 + ct * 64 + lane], Qf1, s, 0, 0, 0);
            S[ct] = s;
        }
        // ---- online softmax (per query r): in-lane 16 + 2 shuffles ----
        float mc = -1e30f;
        #pragma unroll
        for (int ct = 0; ct < 4; ++ct)
            mc = fmaxf(mc, fmaxf(fmaxf(S[ct][0], S[ct][1]),
                                 fmaxf(S[ct][2], S[ct][3])));
        mc = fmaxf(mc, __shfl_xor(mc, 16, 64));
        mc = fmaxf(mc, __shfl_xor(mc, 32, 64));
        const float mnew = fmaxf(mrun, mc);
        const float alpha = __expf(mrun - mnew);
        mrun = mnew;
        float se = 0.f;
        #pragma unroll
        for (int ct = 0; ct < 4; ++ct)
            #pragma unroll
            for (int e = 0; e < 4; ++e) {
                const float pv = __expf(S[ct][e] - mnew);
                S[ct][e] = pv; se += pv;
            }
        se += __shfl_xor(se, 16, 64);
        se += __shfl_xor(se, 32, 64);
        lrun = lrun * alpha + se;
        #pragma unroll
        for (int nt = 0; nt < 4; ++nt)
            #pragma unroll
            for (int e = 0; e < 4; ++e) O[nt][e] *= alpha;
        // ---- P^T -> LDS as P[query][key], packed b64 writes ----
        #pragma unroll
        for (int ct = 0; ct < 4; ++ct) {
            uint2 d;
            d.x = pack_bf2(S[ct][0], S[ct][1]);
            d.y = pack_bf2(S[ct][2], S[ct][3]);
            *(uint2*)(Pw + r * 72 + ct * 16 + q * 4) = d;
        }
        short8 Pf0 = *(const short8*)(Pw + r * 72 + q * 8);
        short8 Pf1 = *(const short8*)(Pw + r * 72 + 32 + q * 8);
        // ---- O^T += MFMA(A=V^T, B=P) ----
        #pragma unroll
        for (int nt = 0; nt < 4; ++nt) {
            O[nt] = __builtin_amdgcn_mfma_f32_16x16x32_bf16(
                Vs[buf][nt * 64 + lane], Pf0, O[nt], 0, 0, 0);
            O[nt] = __builtin_amdgcn_mfma_f32_16x16x32_bf16(
                Vs[buf][256 + nt * 64 + lane], Pf1, O[nt], 0, 0, 0);
        }
        __syncthreads();
    }

    // ---- epilogue: normalize, write ctx[b*512+i][h*64+d], 8B stores ----
    const float inv = 1.0f / lrun;
    const long i = qt * 64 + wid * 16 + r;
    u16* po = ctx + ((long)b * 512 + i) * 1024 + h * 64;
    #pragma unroll
    for (int nt = 0; nt < 4; ++nt) {
        uint2 d;
        d.x = pack_bf2(O[nt][0] * inv, O[nt][1] * inv);
        d.y = pack_bf2(O[nt][2] * inv, O[nt][3] * inv);
        *(uint2*)(po + nt * 16 + q * 4) = d;
    }
}

// ---------------------------------------------------------------------------
// Output projection: out[2048][1024] fp32 = ctx @ Wob^T + bo.
// 64x64 tile, BK=64, both operands via global_load_lds, double-buffered,
// one barrier per step. Waves 2x2; wave = 32m x 32n.
// ---------------------------------------------------------------------------
__global__ __launch_bounds__(256) void gemm_o(
    const u16* __restrict__ A, const u16* __restrict__ B,
    const float* __restrict__ bias, float* __restrict__ C)
{
    __shared__ short8 As[2][512];   // [f*256 + mt*64 + q*16 + r]
    __shared__ short8 Bs[2][512];

    const int tid = threadIdx.x;
    const int lane = tid & 63, wid = tid >> 6;
    const int q = lane >> 4, r = lane & 15;
    const long m0 = (long)blockIdx.x * 64, n0 = (long)blockIdx.y * 64;
    const int wm = wid >> 1, wn = wid & 1;

    const u16* ap[2];
    const u16* bp[2];
    #pragma unroll
    for (int i = 0; i < 2; ++i) {
        const int t = wid * 2 + i, f = t >> 2, mt = t & 3;
        ap[i] = A + (m0 + mt * 16 + r) * 1024 + f * 32 + q * 8;
        bp[i] = B + (n0 + mt * 16 + r) * 1024 + f * 32 + q * 8;
    }

    #pragma unroll
    for (int i = 0; i < 2; ++i) {
        gld16(&As[0][(wid * 2 + i) * 64], ap[i]);
        gld16(&Bs[0][(wid * 2 + i) * 64], bp[i]);
    }
    __syncthreads();

    f32x4 acc[2][2] = {};

    for (int k0 = 0; k0 < 1024; k0 += 64) {
        const int buf = (k0 >> 6) & 1;
        if (k0 + 64 < 1024) {
            #pragma unroll
            for (int i = 0; i < 2; ++i) {
                gld16(&As[buf ^ 1][(wid * 2 + i) * 64], ap[i] + k0 + 64);
                gld16(&Bs[buf ^ 1][(wid * 2 + i) * 64], bp[i] + k0 + 64);
            }
        }
        #pragma unroll
        for (int f = 0; f < 2; ++f) {
            short8 af0 = As[buf][f * 256 + (wm * 2 + 0) * 64 + lane];
            short8 af1 = As[buf][f * 256 + (wm * 2 + 1) * 64 + lane];
            short8 bf0 = Bs[buf][f * 256 + (wn * 2 + 0) * 64 + lane];
            short8 bf1 = Bs[buf][f * 256 + (wn * 2 + 1) * 64 + lane];
            acc[0][0] = __builtin_amdgcn_mfma_f32_16x16x32_bf16(af0, bf0, acc[0][0], 0, 0, 0);
            acc[0][1] = __builtin_amdgcn_mfma_f32_16x16x32_bf16(af0, bf1, acc[0][1], 0, 0, 0);
            acc[1][0] = __builtin_amdgcn_mfma_f32_16x16x32_bf16(af1, bf0, acc[1][0], 0, 0, 0);
            acc[1][1] = __builtin_amdgcn_mfma_f32_16x16x32_bf16(af1, bf1, acc[1][1], 0, 0, 0);
        }
        __syncthreads();
    }

    #pragma unroll
    for (int i = 0; i < 2; ++i)
        #pragma unroll
        for (int j = 0; j < 2; ++j) {
            const long col = n0 + (wn * 2 + j) * 16 + r;
            const float badd = bias[col];
            #pragma unroll
            for (int e = 0; e < 4; ++e) {
                const long row = m0 + (wm * 2 + i) * 16 + q * 4 + e;
                C[row * 1024 + col] = acc[i][j][e] + badd;
            }
        }
}

// ---------------------------------------------------------------------------
extern "C" void kernel_launch(void* const* d_in, const int* in_sizes, int n_in,
                              void* d_out, int out_size, void* d_ws, size_t ws_size,
                              hipStream_t stream)
{
    const float* x  = (const float*)d_in[0];
    const float* Wq = (const float*)d_in[1];
    const float* bq = (const float*)d_in[2];
    const float* Wk = (const float*)d_in[3];
    const float* bk = (const float*)d_in[4];
    const float* Wv = (const float*)d_in[5];
    const float* bv = (const float*)d_in[6];
    const float* Wo = (const float*)d_in[7];
    const float* bo = (const float*)d_in[8];
    float* out = (float*)d_out;
    char* ws = (char*)d_ws;

    u16*   qkv  = (u16*)(ws);                   // 32768*192*2   = 12,582,912
    u16*   Vt   = (u16*)(ws + 12582912);        // 64*64*512*2   =  4,194,304
    u16*   Wqkv = (u16*)(ws + 16777216);        // 192*1024*2    =    393,216
    u16*   Wob  = (u16*)(ws + 17170432);        // 1024*1024*2   =  2,097,152
    float* qkvb = (float*)(ws + 19267584);      // 192*4
    u16*   ctx  = (u16*)(ws + 19268352);        // 2048*1024*2   =  4,194,304

    convw<<<4096, 256, 0, stream>>>(Wq, bq, Wk, bk, Wv, bv, Wo, Wqkv, qkvb, Wob);
    qkv_gemm<<<512, 256, 0, stream>>>(x, Wqkv, qkvb, qkv);
    vtrans<<<dim3(64, 8), 256, 0, stream>>>(qkv, Vt);
    attn_flash<<<dim3(8, 64), 256, 0, stream>>>(qkv, Vt, ctx);
    gemm_o<<<dim3(32, 16), 256, 0, stream>>>(ctx, Wob, bo, out);
}